// Round 2
// baseline (1337.519 us; speedup 1.0000x reference)
//
#include <hip/hip_runtime.h>

#define NN 100000
#define EE 1600000
#define FIN 128
#define FHID 64

// ---------- degree / normalization ----------
__global__ void k_deg_init(float* __restrict__ deg) {
    int i = blockIdx.x * blockDim.x + threadIdx.x;
    if (i < NN) deg[i] = 1.0f;  // self-loop contributes 1
}

__global__ void k_deg_count(const int* __restrict__ col, float* __restrict__ deg) {
    int e = blockIdx.x * blockDim.x + threadIdx.x;
    if (e < EE) atomicAdd(&deg[col[e]], 1.0f);
}

__global__ void k_dinv(float* __restrict__ deg) {
    int i = blockIdx.x * blockDim.x + threadIdx.x;
    if (i < NN) {
        float d = deg[i];
        deg[i] = (d > 0.f) ? (1.0f / sqrtf(d)) : 0.0f;
    }
}

// ---------- GEMM1: h = x @ W1 ; agg = h * dinv^2 (self-loop term) ----------
__global__ __launch_bounds__(256) void k_gemm1(const float* __restrict__ x,
                                               const float* __restrict__ W1,
                                               const float* __restrict__ dinv,
                                               float* __restrict__ h,
                                               float* __restrict__ agg) {
    __shared__ float w[FIN * FHID];  // 32 KiB
    for (int t = threadIdx.x; t < FIN * FHID; t += 256) w[t] = W1[t];
    __syncthreads();
    int wave = threadIdx.x >> 6;
    int lane = threadIdx.x & 63;
    int node = blockIdx.x * 4 + wave;
    if (node >= NN) return;
    // each lane holds 2 consecutive x elements of this node's row
    float2 xv = *reinterpret_cast<const float2*>(&x[(size_t)node * FIN + lane * 2]);
    float acc = 0.f;
#pragma unroll
    for (int k = 0; k < 64; ++k) {
        float a0 = __shfl(xv.x, k);
        float a1 = __shfl(xv.y, k);
        acc += a0 * w[(2 * k) * FHID + lane];
        acc += a1 * w[(2 * k + 1) * FHID + lane];
    }
    float d = dinv[node];
    h[(size_t)node * FHID + lane] = acc;
    agg[(size_t)node * FHID + lane] = acc * d * d;
}

// ---------- GEMM2: reads raw agg1, applies bias+ReLU on the fly ----------
// aggIn and aggOut may be the SAME buffer: each wave reads exactly its own
// row before overwriting it (per-thread data dependence) -> safe.
__global__ __launch_bounds__(256) void k_gemm2(const float* aggIn,
                                               const float* __restrict__ W2,
                                               const float* __restrict__ b1,
                                               const float* __restrict__ dinv,
                                               float* __restrict__ h,
                                               float* aggOut) {
    __shared__ float w[FHID * FHID];  // 16 KiB
    for (int t = threadIdx.x; t < FHID * FHID; t += 256) w[t] = W2[t];
    __syncthreads();
    int wave = threadIdx.x >> 6;
    int lane = threadIdx.x & 63;
    int node = blockIdx.x * 4 + wave;
    if (node >= NN) return;
    float a = aggIn[(size_t)node * FHID + lane] + b1[lane];
    a = fmaxf(a, 0.f);  // ReLU of layer-1 activation
    float acc = 0.f;
#pragma unroll
    for (int k = 0; k < 64; ++k) {
        acc += __shfl(a, k) * w[k * FHID + lane];
    }
    float d = dinv[node];
    h[(size_t)node * FHID + lane] = acc;
    aggOut[(size_t)node * FHID + lane] = acc * d * d;
}

// ---------- edge aggregation: agg[c] += h[r] * dinv[r]*dinv[c] ----------
__global__ __launch_bounds__(256) void k_agg(const int* __restrict__ row,
                                             const int* __restrict__ col,
                                             const float* __restrict__ dinv,
                                             const float* __restrict__ h,
                                             float* __restrict__ agg) {
    int wave = threadIdx.x >> 6;
    int lane = threadIdx.x & 63;
    long long e = (long long)blockIdx.x * 4 + wave;
    if (e >= EE) return;
    int r = row[e];
    int c = col[e];
    float nrm = dinv[r] * dinv[c];
    float v = h[(size_t)r * FHID + lane] * nrm;
    atomicAdd(&agg[(size_t)c * FHID + lane], v);
}

// ---------- link prediction on original edges ----------
__global__ __launch_bounds__(256) void k_link(const int* __restrict__ row,
                                              const int* __restrict__ col,
                                              const float* __restrict__ agg,
                                              const float* __restrict__ b2,
                                              const float* __restrict__ Wout,
                                              const float* __restrict__ bout,
                                              float* __restrict__ out) {
    int wave = threadIdx.x >> 6;
    int lane = threadIdx.x & 63;
    long long e = (long long)blockIdx.x * 4 + wave;
    if (e >= EE) return;
    int r = row[e];
    int c = col[e];
    float bb = b2[lane];
    float wo = Wout[lane];
    float u = fmaxf(agg[(size_t)r * FHID + lane] + bb, 0.f);
    float v = fmaxf(agg[(size_t)c * FHID + lane] + bb, 0.f);
    float p = u * v * wo;
#pragma unroll
    for (int off = 32; off; off >>= 1) p += __shfl_xor(p, off);
    if (lane == 0) out[e] = p + bout[0];
}

extern "C" void kernel_launch(void* const* d_in, const int* in_sizes, int n_in,
                              void* d_out, int out_size, void* d_ws, size_t ws_size,
                              hipStream_t stream) {
    const float* x    = (const float*)d_in[0];
    const int*   ei   = (const int*)d_in[1];   // int64 in reference -> int32 here
    const float* W1   = (const float*)d_in[2];
    const float* b1   = (const float*)d_in[3];
    const float* W2   = (const float*)d_in[4];
    const float* b2   = (const float*)d_in[5];
    const float* Wout = (const float*)d_in[6];
    const float* bout = (const float*)d_in[7];
    const int*   row0 = ei;        // edge_index[0]
    const int*   col0 = ei + EE;   // edge_index[1]

    char* ws = (char*)d_ws;
    // layout: dinv [N] | bufA [N*64] | bufB [N*64]
    const size_t dinvBytes = ((size_t)NN * 4 + 255) / 256 * 256;   // 400128
    const size_t bufBytes  = (size_t)NN * FHID * 4;                // 25,600,000
    float* dinv = (float*)ws;
    float* bufA = (float*)(ws + dinvBytes);
    float* bufB = (float*)(ws + dinvBytes + bufBytes);
    float* out  = (float*)d_out;

    k_deg_init<<<(NN + 255) / 256, 256, 0, stream>>>(dinv);
    k_deg_count<<<(EE + 255) / 256, 256, 0, stream>>>(col0, dinv);
    k_dinv<<<(NN + 255) / 256, 256, 0, stream>>>(dinv);

    // layer 1
    k_gemm1<<<(NN + 3) / 4, 256, 0, stream>>>(x, W1, dinv, bufA, bufB);
    k_agg<<<(EE + 3) / 4, 256, 0, stream>>>(row0, col0, dinv, bufA, bufB);

    // layer 2 (bias+ReLU of layer 1 fused into GEMM2 read)
    k_gemm2<<<(NN + 3) / 4, 256, 0, stream>>>(bufB, W2, b1, dinv, bufA, bufB);
    k_agg<<<(EE + 3) / 4, 256, 0, stream>>>(row0, col0, dinv, bufA, bufB);

    // edge scoring (bias+ReLU of layer 2 fused)
    k_link<<<(EE + 3) / 4, 256, 0, stream>>>(row0, col0, bufB, b2, Wout, bout, out);
}

// Round 3
// 821.497 us; speedup vs baseline: 1.6281x; 1.6281x over previous
//
#include <hip/hip_runtime.h>

#define NN 100000
#define EE 1600000
#define FIN 128
#define FHID 64
#define NBLK_SCAN ((NN + 1023) / 1024)   // 98

// ---------- degree count (int) ----------
__global__ void k_zero_int(int* __restrict__ p, int n) {
    int i = blockIdx.x * blockDim.x + threadIdx.x;
    if (i < n) p[i] = 0;
}

__global__ void k_count(const int* __restrict__ col, int* __restrict__ degi) {
    int e = blockIdx.x * blockDim.x + threadIdx.x;
    if (e < EE) atomicAdd(&degi[col[e]], 1);
}

__global__ void k_dinv(const int* __restrict__ degi, float* __restrict__ dinv) {
    int i = blockIdx.x * blockDim.x + threadIdx.x;
    if (i < NN) dinv[i] = rsqrtf((float)(degi[i] + 1));  // +1 self-loop, always > 0
}

// ---------- prefix scan over degi -> starts (exclusive) ----------
__global__ __launch_bounds__(256) void k_scan1(const int* __restrict__ degi,
                                               int* __restrict__ starts,
                                               int* __restrict__ bsum) {
    __shared__ int ts[256];
    int t = threadIdx.x;
    int base = blockIdx.x * 1024 + t * 4;
    int v[4];
#pragma unroll
    for (int j = 0; j < 4; ++j) {
        int i = base + j;
        v[j] = (i < NN) ? degi[i] : 0;
    }
    int local = v[0] + v[1] + v[2] + v[3];
    ts[t] = local;
    __syncthreads();
    for (int off = 1; off < 256; off <<= 1) {
        int x = (t >= off) ? ts[t - off] : 0;
        __syncthreads();
        ts[t] += x;
        __syncthreads();
    }
    int run = ts[t] - local;  // exclusive prefix of this thread within block
    if (t == 255) bsum[blockIdx.x] = ts[255];
#pragma unroll
    for (int j = 0; j < 4; ++j) {
        int i = base + j;
        if (i < NN) starts[i] = run;
        run += v[j];
    }
}

__global__ __launch_bounds__(256) void k_scan2(int* __restrict__ bsum, int nblk) {
    __shared__ int s[256];
    int t = threadIdx.x;
    int v = (t < nblk) ? bsum[t] : 0;
    s[t] = v;
    __syncthreads();
    for (int off = 1; off < 256; off <<= 1) {
        int x = (t >= off) ? s[t - off] : 0;
        __syncthreads();
        s[t] += x;
        __syncthreads();
    }
    if (t < nblk) bsum[t] = s[t] - v;  // exclusive
}

__global__ void k_scan3(int* __restrict__ starts, const int* __restrict__ bsum,
                        int* __restrict__ cursor) {
    int i = blockIdx.x * blockDim.x + threadIdx.x;
    if (i < NN) {
        int v = starts[i] + bsum[i >> 10];
        starts[i] = v;
        cursor[i] = v;
    }
}

__global__ void k_scatter(const int* __restrict__ row, const int* __restrict__ col,
                          int* __restrict__ cursor, int* __restrict__ csr_src) {
    int e = blockIdx.x * blockDim.x + threadIdx.x;
    if (e < EE) {
        int c = col[e];
        int p = atomicAdd(&cursor[c], 1);
        csr_src[p] = row[e];
    }
}

// ---------- GEMM1: hs = (x @ W1) * dinv  (grid-stride, W in LDS once) ----------
__global__ __launch_bounds__(256) void k_gemm1(const float* __restrict__ x,
                                               const float* __restrict__ W1,
                                               const float* __restrict__ dinv,
                                               float* __restrict__ hs) {
    __shared__ float w[FIN * FHID];  // 32 KiB
    for (int t = threadIdx.x; t < FIN * FHID; t += 256) w[t] = W1[t];
    __syncthreads();
    int wave = threadIdx.x >> 6;
    int lane = threadIdx.x & 63;
    for (int node = blockIdx.x * 4 + wave; node < NN; node += gridDim.x * 4) {
        float2 xv = *reinterpret_cast<const float2*>(&x[(size_t)node * FIN + lane * 2]);
        float acc = 0.f;
#pragma unroll
        for (int k = 0; k < 64; ++k) {
            float a0 = __shfl(xv.x, k);
            float a1 = __shfl(xv.y, k);
            acc += a0 * w[(2 * k) * FHID + lane];
            acc += a1 * w[(2 * k + 1) * FHID + lane];
        }
        hs[(size_t)node * FHID + lane] = acc * dinv[node];
    }
}

// ---------- GEMM2: hs2 = (relu(agg1 + b1) @ W2) * dinv ----------
__global__ __launch_bounds__(256) void k_gemm2(const float* __restrict__ aggIn,
                                               const float* __restrict__ W2,
                                               const float* __restrict__ b1,
                                               const float* __restrict__ dinv,
                                               float* __restrict__ hsOut) {
    __shared__ float w[FHID * FHID];  // 16 KiB
    for (int t = threadIdx.x; t < FHID * FHID; t += 256) w[t] = W2[t];
    __syncthreads();
    int wave = threadIdx.x >> 6;
    int lane = threadIdx.x & 63;
    for (int node = blockIdx.x * 4 + wave; node < NN; node += gridDim.x * 4) {
        float a = fmaxf(aggIn[(size_t)node * FHID + lane] + b1[lane], 0.f);
        float acc = 0.f;
#pragma unroll
        for (int k = 0; k < 64; ++k) {
            acc += __shfl(a, k) * w[k * FHID + lane];
        }
        hsOut[(size_t)node * FHID + lane] = acc * dinv[node];
    }
}

// ---------- CSR aggregation: agg[n] = dinv[n] * (hs[n] + sum_in hs[src]) ----------
__global__ __launch_bounds__(256) void k_gather(const int* __restrict__ starts,
                                                const int* __restrict__ degi,
                                                const int* __restrict__ csr_src,
                                                const float* __restrict__ dinv,
                                                const float* __restrict__ hs,
                                                float* __restrict__ agg) {
    int wave = threadIdx.x >> 6;
    int lane = threadIdx.x & 63;
    int n = blockIdx.x * 4 + wave;
    if (n >= NN) return;
    int s = starts[n];
    int d = degi[n];
    float acc0 = hs[(size_t)n * FHID + lane];
    float acc1 = 0.f, acc2 = 0.f, acc3 = 0.f;
    int k = 0;
    for (; k + 3 < d; k += 4) {
        int r0 = csr_src[s + k];
        int r1 = csr_src[s + k + 1];
        int r2 = csr_src[s + k + 2];
        int r3 = csr_src[s + k + 3];
        acc0 += hs[(size_t)r0 * FHID + lane];
        acc1 += hs[(size_t)r1 * FHID + lane];
        acc2 += hs[(size_t)r2 * FHID + lane];
        acc3 += hs[(size_t)r3 * FHID + lane];
    }
    for (; k < d; ++k) acc0 += hs[(size_t)csr_src[s + k] * FHID + lane];
    agg[(size_t)n * FHID + lane] = dinv[n] * ((acc0 + acc1) + (acc2 + acc3));
}

// ---------- link prediction ----------
__global__ __launch_bounds__(256) void k_link(const int* __restrict__ row,
                                              const int* __restrict__ col,
                                              const float* __restrict__ agg,
                                              const float* __restrict__ b2,
                                              const float* __restrict__ Wout,
                                              const float* __restrict__ bout,
                                              float* __restrict__ out) {
    int wave = threadIdx.x >> 6;
    int lane = threadIdx.x & 63;
    long long e = (long long)blockIdx.x * 4 + wave;
    if (e >= EE) return;
    int r = row[e];
    int c = col[e];
    float bb = b2[lane];
    float wo = Wout[lane];
    float u = fmaxf(agg[(size_t)r * FHID + lane] + bb, 0.f);
    float v = fmaxf(agg[(size_t)c * FHID + lane] + bb, 0.f);
    float p = u * v * wo;
#pragma unroll
    for (int off = 32; off; off >>= 1) p += __shfl_xor(p, off);
    if (lane == 0) out[e] = p + bout[0];
}

extern "C" void kernel_launch(void* const* d_in, const int* in_sizes, int n_in,
                              void* d_out, int out_size, void* d_ws, size_t ws_size,
                              hipStream_t stream) {
    const float* x    = (const float*)d_in[0];
    const int*   ei   = (const int*)d_in[1];   // int64 in reference -> int32 here
    const float* W1   = (const float*)d_in[2];
    const float* b1   = (const float*)d_in[3];
    const float* W2   = (const float*)d_in[4];
    const float* b2   = (const float*)d_in[5];
    const float* Wout = (const float*)d_in[6];
    const float* bout = (const float*)d_in[7];
    const int*   row0 = ei;        // edge_index[0] (source)
    const int*   col0 = ei + EE;   // edge_index[1] (destination)

    char* ws = (char*)d_ws;
    auto align = [](size_t v) { return (v + 255) / 256 * 256; };
    const size_t nInt = align((size_t)NN * 4);
    float* dinv    = (float*)ws;                 ws += nInt;
    int*   degi    = (int*)ws;                   ws += nInt;
    int*   starts  = (int*)ws;                   ws += nInt;
    int*   cursor  = (int*)ws;                   ws += nInt;
    int*   bsum    = (int*)ws;                   ws += align(256 * 4);
    int*   csr_src = (int*)ws;                   ws += align((size_t)EE * 4);
    float* bufA    = (float*)ws;                 ws += (size_t)NN * FHID * 4;
    float* bufB    = (float*)ws;
    float* out     = (float*)d_out;

    // CSR build (once; reused by both layers)
    k_zero_int<<<(NN + 255) / 256, 256, 0, stream>>>(degi, NN);
    k_count<<<(EE + 255) / 256, 256, 0, stream>>>(col0, degi);
    k_scan1<<<NBLK_SCAN, 256, 0, stream>>>(degi, starts, bsum);
    k_scan2<<<1, 256, 0, stream>>>(bsum, NBLK_SCAN);
    k_scan3<<<(NN + 255) / 256, 256, 0, stream>>>(starts, bsum, cursor);
    k_dinv<<<(NN + 255) / 256, 256, 0, stream>>>(degi, dinv);
    k_scatter<<<(EE + 255) / 256, 256, 0, stream>>>(row0, col0, cursor, csr_src);

    // layer 1
    k_gemm1<<<1024, 256, 0, stream>>>(x, W1, dinv, bufA);
    k_gather<<<(NN + 3) / 4, 256, 0, stream>>>(starts, degi, csr_src, dinv, bufA, bufB);

    // layer 2
    k_gemm2<<<1024, 256, 0, stream>>>(bufB, W2, b1, dinv, bufA);
    k_gather<<<(NN + 3) / 4, 256, 0, stream>>>(starts, degi, csr_src, dinv, bufA, bufB);

    // edge scoring
    k_link<<<(EE + 3) / 4, 256, 0, stream>>>(row0, col0, bufB, b2, Wout, bout, out);
}

// Round 4
// 635.816 us; speedup vs baseline: 2.1036x; 1.2920x over previous
//
#include <hip/hip_runtime.h>

#define NN 100000
#define EE 1600000
#define FIN 128
#define FHID 64
#define NBLK_SCAN ((NN + 1023) / 1024)   // 98

// ---------- degree count (int) ----------
__global__ void k_zero_int(int* __restrict__ p, int n) {
    int i = blockIdx.x * blockDim.x + threadIdx.x;
    if (i < n) p[i] = 0;
}

__global__ void k_count(const int* __restrict__ col, int* __restrict__ degi) {
    int e = blockIdx.x * blockDim.x + threadIdx.x;
    if (e < EE) atomicAdd(&degi[col[e]], 1);
}

__global__ void k_dinv(const int* __restrict__ degi, float* __restrict__ dinv) {
    int i = blockIdx.x * blockDim.x + threadIdx.x;
    if (i < NN) dinv[i] = rsqrtf((float)(degi[i] + 1));  // +1 self-loop, always > 0
}

// ---------- prefix scan over degi -> starts (exclusive) ----------
__global__ __launch_bounds__(256) void k_scan1(const int* __restrict__ degi,
                                               int* __restrict__ starts,
                                               int* __restrict__ bsum) {
    __shared__ int ts[256];
    int t = threadIdx.x;
    int base = blockIdx.x * 1024 + t * 4;
    int v[4];
#pragma unroll
    for (int j = 0; j < 4; ++j) {
        int i = base + j;
        v[j] = (i < NN) ? degi[i] : 0;
    }
    int local = v[0] + v[1] + v[2] + v[3];
    ts[t] = local;
    __syncthreads();
    for (int off = 1; off < 256; off <<= 1) {
        int x = (t >= off) ? ts[t - off] : 0;
        __syncthreads();
        ts[t] += x;
        __syncthreads();
    }
    int run = ts[t] - local;  // exclusive prefix of this thread within block
    if (t == 255) bsum[blockIdx.x] = ts[255];
#pragma unroll
    for (int j = 0; j < 4; ++j) {
        int i = base + j;
        if (i < NN) starts[i] = run;
        run += v[j];
    }
}

__global__ __launch_bounds__(256) void k_scan2(int* __restrict__ bsum, int nblk) {
    __shared__ int s[256];
    int t = threadIdx.x;
    int v = (t < nblk) ? bsum[t] : 0;
    s[t] = v;
    __syncthreads();
    for (int off = 1; off < 256; off <<= 1) {
        int x = (t >= off) ? s[t - off] : 0;
        __syncthreads();
        s[t] += x;
        __syncthreads();
    }
    if (t < nblk) bsum[t] = s[t] - v;  // exclusive
}

__global__ void k_scan3(int* __restrict__ starts, const int* __restrict__ bsum,
                        int* __restrict__ cursor) {
    int i = blockIdx.x * blockDim.x + threadIdx.x;
    if (i < NN) {
        int v = starts[i] + bsum[i >> 10];
        starts[i] = v;
        cursor[i] = v;
    }
}

__global__ void k_scatter(const int* __restrict__ row, const int* __restrict__ col,
                          int* __restrict__ cursor, int* __restrict__ csr_src,
                          int* __restrict__ csr_eid) {
    int e = blockIdx.x * blockDim.x + threadIdx.x;
    if (e < EE) {
        int c = col[e];
        int p = atomicAdd(&cursor[c], 1);
        csr_src[p] = row[e];
        csr_eid[p] = e;
    }
}

// ---------- GEMM1: hs = (x @ W1) * dinv  (grid-stride, W in LDS once) ----------
__global__ __launch_bounds__(256) void k_gemm1(const float* __restrict__ x,
                                               const float* __restrict__ W1,
                                               const float* __restrict__ dinv,
                                               float* __restrict__ hs) {
    __shared__ float w[FIN * FHID];  // 32 KiB
    for (int t = threadIdx.x; t < FIN * FHID; t += 256) w[t] = W1[t];
    __syncthreads();
    int wave = threadIdx.x >> 6;
    int lane = threadIdx.x & 63;
    for (int node = blockIdx.x * 4 + wave; node < NN; node += gridDim.x * 4) {
        float2 xv = *reinterpret_cast<const float2*>(&x[(size_t)node * FIN + lane * 2]);
        float acc = 0.f;
#pragma unroll
        for (int k = 0; k < 64; ++k) {
            float a0 = __shfl(xv.x, k);
            float a1 = __shfl(xv.y, k);
            acc += a0 * w[(2 * k) * FHID + lane];
            acc += a1 * w[(2 * k + 1) * FHID + lane];
        }
        hs[(size_t)node * FHID + lane] = acc * dinv[node];
    }
}

// ---------- GEMM2: hs2 = (relu(agg1 + b1) @ W2) * dinv ----------
__global__ __launch_bounds__(256) void k_gemm2(const float* __restrict__ aggIn,
                                               const float* __restrict__ W2,
                                               const float* __restrict__ b1,
                                               const float* __restrict__ dinv,
                                               float* __restrict__ hsOut) {
    __shared__ float w[FHID * FHID];  // 16 KiB
    for (int t = threadIdx.x; t < FHID * FHID; t += 256) w[t] = W2[t];
    __syncthreads();
    int wave = threadIdx.x >> 6;
    int lane = threadIdx.x & 63;
    for (int node = blockIdx.x * 4 + wave; node < NN; node += gridDim.x * 4) {
        float a = fmaxf(aggIn[(size_t)node * FHID + lane] + b1[lane], 0.f);
        float acc = 0.f;
#pragma unroll
        for (int k = 0; k < 64; ++k) {
            acc += __shfl(a, k) * w[k * FHID + lane];
        }
        hsOut[(size_t)node * FHID + lane] = acc * dinv[node];
    }
}

// ---------- CSR aggregation: agg[n] = dinv[n] * (hs[n] + sum_in hs[src]) ----------
// 16 lanes x float4 cover one 256B row; the 4 lane-groups process 4 rows per
// wave-instruction (4x load MLP vs one-row-per-instr).
__global__ __launch_bounds__(256) void k_gather(const int* __restrict__ starts,
                                                const int* __restrict__ degi,
                                                const int* __restrict__ csr_src,
                                                const float* __restrict__ dinv,
                                                const float* __restrict__ hs,
                                                float* __restrict__ agg) {
    int wave = threadIdx.x >> 6;
    int lane = threadIdx.x & 63;
    int g = lane >> 4;        // row-group 0..3
    int fl = lane & 15;       // feature quad 0..15
    int n = blockIdx.x * 4 + wave;
    if (n >= NN) return;
    int s = starts[n];
    int d = degi[n];
    const float4* hs4 = reinterpret_cast<const float4*>(hs);
    float4 acc = {0.f, 0.f, 0.f, 0.f};
    if (g == 0) acc = hs4[(size_t)n * 16 + fl];  // self term
    for (int k = g; k < d; k += 4) {
        int r = csr_src[s + k];
        float4 v = hs4[(size_t)r * 16 + fl];
        acc.x += v.x; acc.y += v.y; acc.z += v.z; acc.w += v.w;
    }
    // reduce the 4 row-groups (lanes xor 16, 32)
    acc.x += __shfl_xor(acc.x, 16); acc.y += __shfl_xor(acc.y, 16);
    acc.z += __shfl_xor(acc.z, 16); acc.w += __shfl_xor(acc.w, 16);
    acc.x += __shfl_xor(acc.x, 32); acc.y += __shfl_xor(acc.y, 32);
    acc.z += __shfl_xor(acc.z, 32); acc.w += __shfl_xor(acc.w, 32);
    if (g == 0) {
        float dn = dinv[n];
        float4 o = {acc.x * dn, acc.y * dn, acc.z * dn, acc.w * dn};
        reinterpret_cast<float4*>(agg)[(size_t)n * 16 + fl] = o;
    }
}

// ---------- link prediction, CSR order (grouped by destination) ----------
// score(e) = sum_f relu(agg[r]+b2)[f] * relu(agg[c]+b2)[f] * Wout[f] + bout
// Per node c: ucw = relu(agg[c]+b2)*Wout held in registers; per in-edge only
// agg[r] is gathered (halves random traffic vs edge-order).
__global__ __launch_bounds__(256) void k_link(const int* __restrict__ starts,
                                              const int* __restrict__ degi,
                                              const int* __restrict__ csr_src,
                                              const int* __restrict__ csr_eid,
                                              const float* __restrict__ agg,
                                              const float* __restrict__ b2,
                                              const float* __restrict__ Wout,
                                              const float* __restrict__ bout,
                                              float* __restrict__ out) {
    int wave = threadIdx.x >> 6;
    int lane = threadIdx.x & 63;
    int g = lane >> 4;
    int fl = lane & 15;
    int n = blockIdx.x * 4 + wave;
    if (n >= NN) return;
    int d = degi[n];
    if (d == 0) return;
    int s = starts[n];
    const float4* a4 = reinterpret_cast<const float4*>(agg);
    float4 b2v = reinterpret_cast<const float4*>(b2)[fl];
    float4 wov = reinterpret_cast<const float4*>(Wout)[fl];
    float4 ac = a4[(size_t)n * 16 + fl];
    float4 ucw;
    ucw.x = fmaxf(ac.x + b2v.x, 0.f) * wov.x;
    ucw.y = fmaxf(ac.y + b2v.y, 0.f) * wov.y;
    ucw.z = fmaxf(ac.z + b2v.z, 0.f) * wov.z;
    ucw.w = fmaxf(ac.w + b2v.w, 0.f) * wov.w;
    float bout0 = bout[0];
    for (int k = g; k < d; k += 4) {
        int r = csr_src[s + k];
        float4 ar = a4[(size_t)r * 16 + fl];
        float p = fmaxf(ar.x + b2v.x, 0.f) * ucw.x;
        p += fmaxf(ar.y + b2v.y, 0.f) * ucw.y;
        p += fmaxf(ar.z + b2v.z, 0.f) * ucw.z;
        p += fmaxf(ar.w + b2v.w, 0.f) * ucw.w;
        // sum over the 16 lanes of this group (features)
        p += __shfl_xor(p, 1);
        p += __shfl_xor(p, 2);
        p += __shfl_xor(p, 4);
        p += __shfl_xor(p, 8);
        if (fl == 0) out[csr_eid[s + k]] = p + bout0;
    }
}

extern "C" void kernel_launch(void* const* d_in, const int* in_sizes, int n_in,
                              void* d_out, int out_size, void* d_ws, size_t ws_size,
                              hipStream_t stream) {
    const float* x    = (const float*)d_in[0];
    const int*   ei   = (const int*)d_in[1];   // int64 in reference -> int32 here
    const float* W1   = (const float*)d_in[2];
    const float* b1   = (const float*)d_in[3];
    const float* W2   = (const float*)d_in[4];
    const float* b2   = (const float*)d_in[5];
    const float* Wout = (const float*)d_in[6];
    const float* bout = (const float*)d_in[7];
    const int*   row0 = ei;        // edge_index[0] (source)
    const int*   col0 = ei + EE;   // edge_index[1] (destination)

    char* ws = (char*)d_ws;
    auto align = [](size_t v) { return (v + 255) / 256 * 256; };
    const size_t nInt = align((size_t)NN * 4);
    float* dinv    = (float*)ws;                 ws += nInt;
    int*   degi    = (int*)ws;                   ws += nInt;
    int*   starts  = (int*)ws;                   ws += nInt;
    int*   cursor  = (int*)ws;                   ws += nInt;
    int*   bsum    = (int*)ws;                   ws += align(256 * 4);
    int*   csr_src = (int*)ws;                   ws += align((size_t)EE * 4);
    int*   csr_eid = (int*)ws;                   ws += align((size_t)EE * 4);
    float* bufA    = (float*)ws;                 ws += (size_t)NN * FHID * 4;
    float* bufB    = (float*)ws;
    float* out     = (float*)d_out;

    // CSR build (once; reused by both layers + link)
    k_zero_int<<<(NN + 255) / 256, 256, 0, stream>>>(degi, NN);
    k_count<<<(EE + 255) / 256, 256, 0, stream>>>(col0, degi);
    k_scan1<<<NBLK_SCAN, 256, 0, stream>>>(degi, starts, bsum);
    k_scan2<<<1, 256, 0, stream>>>(bsum, NBLK_SCAN);
    k_scan3<<<(NN + 255) / 256, 256, 0, stream>>>(starts, bsum, cursor);
    k_dinv<<<(NN + 255) / 256, 256, 0, stream>>>(degi, dinv);
    k_scatter<<<(EE + 255) / 256, 256, 0, stream>>>(row0, col0, cursor, csr_src, csr_eid);

    // layer 1
    k_gemm1<<<1024, 256, 0, stream>>>(x, W1, dinv, bufA);
    k_gather<<<(NN + 3) / 4, 256, 0, stream>>>(starts, degi, csr_src, dinv, bufA, bufB);

    // layer 2
    k_gemm2<<<1024, 256, 0, stream>>>(bufB, W2, b1, dinv, bufA);
    k_gather<<<(NN + 3) / 4, 256, 0, stream>>>(starts, degi, csr_src, dinv, bufA, bufB);

    // edge scoring (CSR order, scattered per-edge writes)
    k_link<<<(NN + 3) / 4, 256, 0, stream>>>(starts, degi, csr_src, csr_eid,
                                             bufB, b2, Wout, bout, out);
}

// Round 5
// 532.053 us; speedup vs baseline: 2.5139x; 1.1950x over previous
//
#include <hip/hip_runtime.h>

#define NN 100000
#define EE 1600000
#define FIN 128
#define FHID 64
#define NBLK_SCAN ((NN + 1023) / 1024)   // 98

// ---------- degree count (int) ----------
__global__ void k_zero_int(int* __restrict__ p, int n) {
    int i = blockIdx.x * blockDim.x + threadIdx.x;
    if (i < n) p[i] = 0;
}

__global__ void k_count(const int* __restrict__ col, int* __restrict__ degi) {
    int e = blockIdx.x * blockDim.x + threadIdx.x;
    if (e < EE) atomicAdd(&degi[col[e]], 1);
}

__global__ void k_dinv(const int* __restrict__ degi, float* __restrict__ dinv) {
    int i = blockIdx.x * blockDim.x + threadIdx.x;
    if (i < NN) dinv[i] = rsqrtf((float)(degi[i] + 1));  // +1 self-loop, always > 0
}

// ---------- prefix scan over degi -> starts (exclusive) ----------
__global__ __launch_bounds__(256) void k_scan1(const int* __restrict__ degi,
                                               int* __restrict__ starts,
                                               int* __restrict__ bsum) {
    __shared__ int ts[256];
    int t = threadIdx.x;
    int base = blockIdx.x * 1024 + t * 4;
    int v[4];
#pragma unroll
    for (int j = 0; j < 4; ++j) {
        int i = base + j;
        v[j] = (i < NN) ? degi[i] : 0;
    }
    int local = v[0] + v[1] + v[2] + v[3];
    ts[t] = local;
    __syncthreads();
    for (int off = 1; off < 256; off <<= 1) {
        int x = (t >= off) ? ts[t - off] : 0;
        __syncthreads();
        ts[t] += x;
        __syncthreads();
    }
    int run = ts[t] - local;  // exclusive prefix of this thread within block
    if (t == 255) bsum[blockIdx.x] = ts[255];
#pragma unroll
    for (int j = 0; j < 4; ++j) {
        int i = base + j;
        if (i < NN) starts[i] = run;
        run += v[j];
    }
}

__global__ __launch_bounds__(256) void k_scan2(int* __restrict__ bsum, int nblk) {
    __shared__ int s[256];
    int t = threadIdx.x;
    int v = (t < nblk) ? bsum[t] : 0;
    s[t] = v;
    __syncthreads();
    for (int off = 1; off < 256; off <<= 1) {
        int x = (t >= off) ? s[t - off] : 0;
        __syncthreads();
        s[t] += x;
        __syncthreads();
    }
    if (t < nblk) bsum[t] = s[t] - v;  // exclusive
}

__global__ void k_scan3(int* __restrict__ starts, const int* __restrict__ bsum,
                        int* __restrict__ cursor) {
    int i = blockIdx.x * blockDim.x + threadIdx.x;
    if (i < NN) {
        int v = starts[i] + bsum[i >> 10];
        starts[i] = v;
        cursor[i] = v;
    }
}

__global__ void k_scatter(const int* __restrict__ row, const int* __restrict__ col,
                          int* __restrict__ cursor, int* __restrict__ csr_src,
                          int* __restrict__ csr_eid) {
    int e = blockIdx.x * blockDim.x + threadIdx.x;
    if (e < EE) {
        int c = col[e];
        int p = atomicAdd(&cursor[c], 1);
        csr_src[p] = row[e];
        csr_eid[p] = e;
    }
}

// ---------- GEMM1: hs = (x @ W1) * dinv ----------
// One wave per 64-node tile. lane = node. acc[64] = all output cols.
// Inner loop: 1 LDS read (x[lane][k]) + 64 FMA with W from uniform scalar
// loads (SGPR operand) -> zero DS ops for W.
#define XPAD 129   // 128 + 1: bank = (129*n + k) % 32 = (n + k) % 32 -> 2-way max
#define OPAD 65    // 64 + 1 for the output transpose
__global__ __launch_bounds__(64) void k_gemm1(const float* __restrict__ x,
                                              const float* __restrict__ W1,
                                              const float* __restrict__ dinv,
                                              float* __restrict__ hs) {
    __shared__ float xl[64 * XPAD];  // 33 KB
    int lane = threadIdx.x;
    int n0 = blockIdx.x * 64;
    const float4* x4 = reinterpret_cast<const float4*>(x);
    // stage 64x128 tile, coalesced reads, padded LDS writes
#pragma unroll
    for (int i = 0; i < 32; ++i) {
        int idx = i * 64 + lane;
        int row = idx >> 5;       // node within tile
        int k4 = idx & 31;        // float4 index along K
        float4 v = {0.f, 0.f, 0.f, 0.f};
        if (n0 + row < NN) v = x4[(size_t)(n0 + row) * 32 + k4];
        float* p = &xl[row * XPAD + k4 * 4];
        p[0] = v.x; p[1] = v.y; p[2] = v.z; p[3] = v.w;
    }
    __syncthreads();

    float acc[64];
#pragma unroll
    for (int c = 0; c < 64; ++c) acc[c] = 0.f;

    for (int k = 0; k < FIN; ++k) {
        float xk = xl[lane * XPAD + k];
        const float* wr = W1 + k * FHID;   // uniform address -> s_load
#pragma unroll
        for (int c = 0; c < 64; ++c) acc[c] = fmaf(xk, wr[c], acc[c]);
    }

    // epilogue: *dinv, transpose through LDS, coalesced store
    float dn = (n0 + lane < NN) ? dinv[n0 + lane] : 0.f;
    __syncthreads();
#pragma unroll
    for (int c = 0; c < 64; ++c) xl[lane * OPAD + c] = acc[c] * dn;
    __syncthreads();
    float4* hs4 = reinterpret_cast<float4*>(hs);
#pragma unroll
    for (int i = 0; i < 16; ++i) {
        int idx = i * 64 + lane;
        int row = idx >> 4;
        int c4 = idx & 15;
        if (n0 + row < NN) {
            const float* p = &xl[row * OPAD + c4 * 4];
            float4 o = {p[0], p[1], p[2], p[3]};
            hs4[(size_t)(n0 + row) * 16 + c4] = o;
        }
    }
}

// ---------- GEMM2: hs2 = (relu(aggIn + b1) @ W2) * dinv ----------
__global__ __launch_bounds__(64) void k_gemm2(const float* __restrict__ aggIn,
                                              const float* __restrict__ W2,
                                              const float* __restrict__ b1,
                                              const float* __restrict__ dinv,
                                              float* __restrict__ hsOut) {
    __shared__ float al[64 * OPAD];  // 16.6 KB
    int lane = threadIdx.x;
    int n0 = blockIdx.x * 64;
    const float4* a4 = reinterpret_cast<const float4*>(aggIn);
    const float4* b14 = reinterpret_cast<const float4*>(b1);
#pragma unroll
    for (int i = 0; i < 16; ++i) {
        int idx = i * 64 + lane;
        int row = idx >> 4;
        int k4 = idx & 15;
        float4 v = {0.f, 0.f, 0.f, 0.f};
        if (n0 + row < NN) {
            float4 a = a4[(size_t)(n0 + row) * 16 + k4];
            float4 b = b14[k4];
            v.x = fmaxf(a.x + b.x, 0.f);
            v.y = fmaxf(a.y + b.y, 0.f);
            v.z = fmaxf(a.z + b.z, 0.f);
            v.w = fmaxf(a.w + b.w, 0.f);
        }
        float* p = &al[row * OPAD + k4 * 4];
        p[0] = v.x; p[1] = v.y; p[2] = v.z; p[3] = v.w;
    }
    __syncthreads();

    float acc[64];
#pragma unroll
    for (int c = 0; c < 64; ++c) acc[c] = 0.f;

    for (int k = 0; k < FHID; ++k) {
        float xk = al[lane * OPAD + k];
        const float* wr = W2 + k * FHID;
#pragma unroll
        for (int c = 0; c < 64; ++c) acc[c] = fmaf(xk, wr[c], acc[c]);
    }

    float dn = (n0 + lane < NN) ? dinv[n0 + lane] : 0.f;
    __syncthreads();
#pragma unroll
    for (int c = 0; c < 64; ++c) al[lane * OPAD + c] = acc[c] * dn;
    __syncthreads();
    float4* o4 = reinterpret_cast<float4*>(hsOut);
#pragma unroll
    for (int i = 0; i < 16; ++i) {
        int idx = i * 64 + lane;
        int row = idx >> 4;
        int c4 = idx & 15;
        if (n0 + row < NN) {
            const float* p = &al[row * OPAD + c4 * 4];
            float4 o = {p[0], p[1], p[2], p[3]};
            o4[(size_t)(n0 + row) * 16 + c4] = o;
        }
    }
}

// ---------- CSR aggregation: agg[n] = dinv[n] * (hs[n] + sum_in hs[src]) ----------
__global__ __launch_bounds__(256) void k_gather(const int* __restrict__ starts,
                                                const int* __restrict__ degi,
                                                const int* __restrict__ csr_src,
                                                const float* __restrict__ dinv,
                                                const float* __restrict__ hs,
                                                float* __restrict__ agg) {
    int wave = threadIdx.x >> 6;
    int lane = threadIdx.x & 63;
    int g = lane >> 4;        // row-group 0..3
    int fl = lane & 15;       // feature quad 0..15
    int n = blockIdx.x * 4 + wave;
    if (n >= NN) return;
    int s = starts[n];
    int d = degi[n];
    const float4* hs4 = reinterpret_cast<const float4*>(hs);
    float4 acc = {0.f, 0.f, 0.f, 0.f};
    if (g == 0) acc = hs4[(size_t)n * 16 + fl];  // self term
    for (int k = g; k < d; k += 4) {
        int r = csr_src[s + k];
        float4 v = hs4[(size_t)r * 16 + fl];
        acc.x += v.x; acc.y += v.y; acc.z += v.z; acc.w += v.w;
    }
    acc.x += __shfl_xor(acc.x, 16); acc.y += __shfl_xor(acc.y, 16);
    acc.z += __shfl_xor(acc.z, 16); acc.w += __shfl_xor(acc.w, 16);
    acc.x += __shfl_xor(acc.x, 32); acc.y += __shfl_xor(acc.y, 32);
    acc.z += __shfl_xor(acc.z, 32); acc.w += __shfl_xor(acc.w, 32);
    if (g == 0) {
        float dn = dinv[n];
        float4 o = {acc.x * dn, acc.y * dn, acc.z * dn, acc.w * dn};
        reinterpret_cast<float4*>(agg)[(size_t)n * 16 + fl] = o;
    }
}

// ---------- link prediction, CSR order (grouped by destination) ----------
__global__ __launch_bounds__(256) void k_link(const int* __restrict__ starts,
                                              const int* __restrict__ degi,
                                              const int* __restrict__ csr_src,
                                              const int* __restrict__ csr_eid,
                                              const float* __restrict__ agg,
                                              const float* __restrict__ b2,
                                              const float* __restrict__ Wout,
                                              const float* __restrict__ bout,
                                              float* __restrict__ out) {
    int wave = threadIdx.x >> 6;
    int lane = threadIdx.x & 63;
    int g = lane >> 4;
    int fl = lane & 15;
    int n = blockIdx.x * 4 + wave;
    if (n >= NN) return;
    int d = degi[n];
    if (d == 0) return;
    int s = starts[n];
    const float4* a4 = reinterpret_cast<const float4*>(agg);
    float4 b2v = reinterpret_cast<const float4*>(b2)[fl];
    float4 wov = reinterpret_cast<const float4*>(Wout)[fl];
    float4 ac = a4[(size_t)n * 16 + fl];
    float4 ucw;
    ucw.x = fmaxf(ac.x + b2v.x, 0.f) * wov.x;
    ucw.y = fmaxf(ac.y + b2v.y, 0.f) * wov.y;
    ucw.z = fmaxf(ac.z + b2v.z, 0.f) * wov.z;
    ucw.w = fmaxf(ac.w + b2v.w, 0.f) * wov.w;
    float bout0 = bout[0];
    for (int k = g; k < d; k += 4) {
        int r = csr_src[s + k];
        float4 ar = a4[(size_t)r * 16 + fl];
        float p = fmaxf(ar.x + b2v.x, 0.f) * ucw.x;
        p += fmaxf(ar.y + b2v.y, 0.f) * ucw.y;
        p += fmaxf(ar.z + b2v.z, 0.f) * ucw.z;
        p += fmaxf(ar.w + b2v.w, 0.f) * ucw.w;
        p += __shfl_xor(p, 1);
        p += __shfl_xor(p, 2);
        p += __shfl_xor(p, 4);
        p += __shfl_xor(p, 8);
        if (fl == 0) out[csr_eid[s + k]] = p + bout0;
    }
}

extern "C" void kernel_launch(void* const* d_in, const int* in_sizes, int n_in,
                              void* d_out, int out_size, void* d_ws, size_t ws_size,
                              hipStream_t stream) {
    const float* x    = (const float*)d_in[0];
    const int*   ei   = (const int*)d_in[1];   // int64 in reference -> int32 here
    const float* W1   = (const float*)d_in[2];
    const float* b1   = (const float*)d_in[3];
    const float* W2   = (const float*)d_in[4];
    const float* b2   = (const float*)d_in[5];
    const float* Wout = (const float*)d_in[6];
    const float* bout = (const float*)d_in[7];
    const int*   row0 = ei;        // edge_index[0] (source)
    const int*   col0 = ei + EE;   // edge_index[1] (destination)

    char* ws = (char*)d_ws;
    auto align = [](size_t v) { return (v + 255) / 256 * 256; };
    const size_t nInt = align((size_t)NN * 4);
    float* dinv    = (float*)ws;                 ws += nInt;
    int*   degi    = (int*)ws;                   ws += nInt;
    int*   starts  = (int*)ws;                   ws += nInt;
    int*   cursor  = (int*)ws;                   ws += nInt;
    int*   bsum    = (int*)ws;                   ws += align(256 * 4);
    int*   csr_src = (int*)ws;                   ws += align((size_t)EE * 4);
    int*   csr_eid = (int*)ws;                   ws += align((size_t)EE * 4);
    float* bufA    = (float*)ws;                 ws += (size_t)NN * FHID * 4;
    float* bufB    = (float*)ws;
    float* out     = (float*)d_out;

    const int nTiles = (NN + 63) / 64;  // 1563

    // CSR build (once; reused by both layers + link)
    k_zero_int<<<(NN + 255) / 256, 256, 0, stream>>>(degi, NN);
    k_count<<<(EE + 255) / 256, 256, 0, stream>>>(col0, degi);
    k_scan1<<<NBLK_SCAN, 256, 0, stream>>>(degi, starts, bsum);
    k_scan2<<<1, 256, 0, stream>>>(bsum, NBLK_SCAN);
    k_scan3<<<(NN + 255) / 256, 256, 0, stream>>>(starts, bsum, cursor);
    k_dinv<<<(NN + 255) / 256, 256, 0, stream>>>(degi, dinv);
    k_scatter<<<(EE + 255) / 256, 256, 0, stream>>>(row0, col0, cursor, csr_src, csr_eid);

    // layer 1
    k_gemm1<<<nTiles, 64, 0, stream>>>(x, W1, dinv, bufA);
    k_gather<<<(NN + 3) / 4, 256, 0, stream>>>(starts, degi, csr_src, dinv, bufA, bufB);

    // layer 2
    k_gemm2<<<nTiles, 64, 0, stream>>>(bufB, W2, b1, dinv, bufA);
    k_gather<<<(NN + 3) / 4, 256, 0, stream>>>(starts, degi, csr_src, dinv, bufA, bufB);

    // edge scoring (CSR order, scattered per-edge writes)
    k_link<<<(NN + 3) / 4, 256, 0, stream>>>(starts, degi, csr_src, csr_eid,
                                             bufB, b2, Wout, bout, out);
}